// Round 3
// baseline (240.585 us; speedup 1.0000x reference)
//
#include <hip/hip_runtime.h>
#include <math.h>

#define BB 16
#define NN 25200
#define NCLS 80
#define TOPK 1000
#define MAXDET 100
#define TIE_CAP 2048
#define CAND_CAP 1024
static constexpr float NEGV = -1000000000.0f;
static constexpr float IMGSZ = 640.0f;

struct Meta {
  unsigned b1;
  unsigned c_gt;
  unsigned K;
  unsigned ties_needed;
  unsigned cnt;
  unsigned tie_cnt;
  unsigned n_cand;
  unsigned pad;
};

__device__ __forceinline__ unsigned flipKey(float f) {
  unsigned u = __float_as_uint(f);
  return (u & 0x80000000u) ? ~u : (u | 0x80000000u);
}
__device__ __forceinline__ float unflipKey(unsigned k) {
  unsigned u = (k & 0x80000000u) ? (k & 0x7FFFFFFFu) : ~k;
  return __uint_as_float(u);
}

// 32-bit unsigned max DPP step (bound_ctrl=1 -> invalid lanes read 0 = identity)
#define UMAX_DPP(VAR, CTRL)                                                              \
  {                                                                                      \
    unsigned _o = (unsigned)__builtin_amdgcn_update_dpp(0, (int)(VAR), CTRL, 0xF, 0xF, true); \
    if (_o > (VAR)) (VAR) = _o;                                                          \
  }

// (hi,lo) 64-bit-ordered max DPP step
#define U64MAX_DPP(H, L, CTRL)                                                           \
  {                                                                                      \
    unsigned _oh = (unsigned)__builtin_amdgcn_update_dpp(0, (int)(H), CTRL, 0xF, 0xF, true); \
    unsigned _ol = (unsigned)__builtin_amdgcn_update_dpp(0, (int)(L), CTRL, 0xF, 0xF, true); \
    bool _g = (_oh > (H)) || ((_oh == (H)) && (_ol > (L)));                              \
    (H) = _g ? _oh : (H);                                                                \
    (L) = _g ? _ol : (L);                                                                \
  }

// ---------------- phase 1: scores + high-16 histogram (4 lanes per row) ----------------
__global__ void __launch_bounds__(256) k_score(const float* __restrict__ regs,
                                               const float* __restrict__ clses,
                                               unsigned* __restrict__ keys,
                                               float* __restrict__ ccs,
                                               int* __restrict__ preds,
                                               unsigned* __restrict__ hist1) {
  int t = blockIdx.x * 256 + threadIdx.x;
  int row = t >> 2, q = t & 3;
  const float4* r4 = reinterpret_cast<const float4*>(clses + (size_t)row * NCLS);
  float best = -1.0f;
  int bi = 0;
#pragma unroll
  for (int u = 0; u < 5; ++u) {
    float4 v = r4[q + 4 * u];
    int b0 = (q + 4 * u) * 4;
    if (v.x > best) { best = v.x; bi = b0 + 0; }
    if (v.y > best) { best = v.y; bi = b0 + 1; }
    if (v.z > best) { best = v.z; bi = b0 + 2; }
    if (v.w > best) { best = v.w; bi = b0 + 3; }
  }
  // quad butterfly: value stage (positive-float bits are unsigned-orderable)
  unsigned vb = __float_as_uint(best);
  unsigned m = vb;
  UMAX_DPP(m, 0xB1);  // quad_perm [1,0,3,2] = xor 1
  UMAX_DPP(m, 0x4E);  // quad_perm [2,3,0,1] = xor 2
  // tie stage: among lanes matching max value, smallest class index wins
  unsigned t2 = (vb == m) ? (unsigned)(79 - bi) : 0u;
  UMAX_DPP(t2, 0xB1);
  UMAX_DPP(t2, 0x4E);
  if (q == 0) {
    float bestv = __uint_as_float(m);
    int bidx = 79 - (int)t2;
    float pobj = regs[(size_t)row * 5 + 4];
    float sc = pobj * bestv;
    float s = (sc >= 0.05f) ? sc : NEGV;
    unsigned key = flipKey(s);
    keys[row] = key;
    ccs[row] = bestv;
    preds[row] = bidx;
    int img = row / NN;
    atomicAdd(&hist1[(size_t)img * 65536 + (key >> 16)], 1u);
  }
}

// ---------------- histogram scan: parallel suffix-scan radix select ----------------
__global__ void __launch_bounds__(256) k_scan(const unsigned* __restrict__ hist,
                                              Meta* __restrict__ meta, int phase) {
  __shared__ unsigned part[256];
  __shared__ unsigned sfx[256];
  __shared__ int s_sel;
  __shared__ unsigned s_cum;
  int img = blockIdx.x;
  int t = threadIdx.x;
  const unsigned* h = hist + (size_t)img * 65536;
  unsigned cgt_prev = (phase == 1) ? 0u : meta[img].c_gt;
  unsigned target = (unsigned)TOPK - cgt_prev;
  unsigned s = 0;
  const uint4* h4 = reinterpret_cast<const uint4*>(h) + (size_t)t * 64;
  for (int j = 0; j < 64; ++j) {
    uint4 v = h4[j];
    s += v.x + v.y + v.z + v.w;
  }
  part[t] = s;
  sfx[t] = s;
  __syncthreads();
  for (int d = 1; d < 256; d <<= 1) {
    unsigned v = (t + d < 256) ? sfx[t + d] : 0u;
    __syncthreads();
    sfx[t] += v;
    __syncthreads();
  }
  {
    unsigned incl = sfx[t];
    unsigned excl = incl - part[t];
    if (incl >= target && excl < target) { s_sel = t; s_cum = excl; }
  }
  __syncthreads();
  int chunk = s_sel;
  unsigned cumAbove = s_cum;
  __syncthreads();
  unsigned b = h[(size_t)chunk * 256 + t];
  part[t] = b;
  sfx[t] = b;
  __syncthreads();
  for (int d = 1; d < 256; d <<= 1) {
    unsigned v = (t + d < 256) ? sfx[t + d] : 0u;
    __syncthreads();
    sfx[t] += v;
    __syncthreads();
  }
  {
    unsigned incl = cumAbove + sfx[t];
    unsigned excl = incl - part[t];
    if (incl >= target && excl < target) {
      if (phase == 1) {
        meta[img].b1 = (unsigned)(chunk * 256 + t);
        meta[img].c_gt = excl;
      } else {
        meta[img].K = (meta[img].b1 << 16) | (unsigned)(chunk * 256 + t);
        meta[img].ties_needed = target - excl;
      }
    }
  }
}

// ---------------- phase 2: low-16 histogram of cutoff bin ----------------
__global__ void k_hist2(const unsigned* __restrict__ keys, const Meta* __restrict__ meta,
                        unsigned* __restrict__ hist2) {
  int g = blockIdx.x * blockDim.x + threadIdx.x;
  if (g >= BB * NN) return;
  int img = g / NN;
  unsigned key = keys[g];
  if ((key >> 16) == meta[img].b1)
    atomicAdd(&hist2[(size_t)img * 65536 + (key & 0xFFFFu)], 1u);
}

// ---------------- decode + candidate write ----------------
__device__ __forceinline__ void decode_write(int img, unsigned pos, int i,
                                             const float* __restrict__ regs,
                                             const float* __restrict__ anchors,
                                             float score, float cc, int pred,
                                             float* __restrict__ cand) {
  const size_t S = (size_t)BB * CAND_CAP;
  size_t g = (size_t)img * NN + (size_t)i;
  const float* r = regs + g * 5;
  float d0 = r[0], d1 = r[1], d2 = r[2], d3 = r[3], obj = r[4];
  const float* a = anchors + (size_t)i * 4;
  float ax1 = a[0], ay1 = a[1], ax2 = a[2], ay2 = a[3];
  float aw = ax2 - ax1, ah = ay2 - ay1;
  float acx = (ax1 + ax2) * 0.5f, acy = (ay1 + ay2) * 0.5f;
  float cx = acx + d0 * aw, cy = acy + d1 * ah;
  float w = aw * expf(d2), h = ah * expf(d3);
  float hw = 0.5f * w, hh = 0.5f * h;
  float x1 = fminf(fmaxf(cx - hw, 0.0f), IMGSZ);
  float y1 = fminf(fmaxf(cy - hh, 0.0f), IMGSZ);
  float x2 = fminf(fmaxf(cx + hw, 0.0f), IMGSZ);
  float y2 = fminf(fmaxf(cy + hh, 0.0f), IMGSZ);
  size_t o = (size_t)img * CAND_CAP + pos;
  cand[0 * S + o] = x1;
  cand[1 * S + o] = y1;
  cand[2 * S + o] = x2;
  cand[3 * S + o] = y2;
  cand[4 * S + o] = obj;
  cand[5 * S + o] = cc;
  cand[6 * S + o] = (float)pred;
  cand[7 * S + o] = score;
  reinterpret_cast<unsigned*>(cand + 8 * S)[o] = (unsigned)i;
}

// ---------------- compaction ----------------
__global__ void k_compact(const float* __restrict__ regs, const float* __restrict__ anchors,
                          const unsigned* __restrict__ keys, const float* __restrict__ ccs,
                          const int* __restrict__ preds, Meta* __restrict__ meta,
                          float* __restrict__ cand, unsigned* __restrict__ ties) {
  int g = blockIdx.x * blockDim.x + threadIdx.x;
  if (g >= BB * NN) return;
  int img = g / NN;
  int i = g - img * NN;
  unsigned key = keys[g];
  unsigned K = meta[img].K;
  if (key > K) {
    unsigned pos = atomicAdd(&meta[img].cnt, 1u);
    if (pos < CAND_CAP)
      decode_write(img, pos, i, regs, anchors, unflipKey(key), ccs[g], preds[g], cand);
  } else if (key == K) {
    unsigned tp = atomicAdd(&meta[img].tie_cnt, 1u);
    if (tp < TIE_CAP) ties[(size_t)img * TIE_CAP + tp] = (unsigned)i;
  }
}

// ---------------- NMS (+ inlined tie resolution): one block (4 waves) per image ----------
// Order key: hi = flipKey(score), lo = (0x7FFF - anchor_idx)<<10 | slot.
// Wave argmax = 6 DPP steps (VALU-only), cross-wave combine = 1 LDS word/wave + 1 barrier.
// Suppression test RN(i/u) > 0.5 replaced by exact-equivalent 2i - u > u*2^-24 (no div).
__global__ void __launch_bounds__(256) k_nms(float* __restrict__ cand,
                                             Meta* __restrict__ meta,
                                             float* __restrict__ out,
                                             const float* __restrict__ regs,
                                             const float* __restrict__ anchors,
                                             const float* __restrict__ ccs,
                                             const int* __restrict__ preds,
                                             const unsigned* __restrict__ ties) {
  const size_t S = (size_t)BB * CAND_CAP;
  int img = blockIdx.x;
  int tid = threadIdx.x;
  int lane = tid & 63;
  int wid = tid >> 6;

  __shared__ float lds[CAND_CAP * 12];  // x1o,y1o,x2o,y2o,area, x1,y1,x2,y2,obj,cc,cp
  __shared__ unsigned redu[256];
  __shared__ unsigned swh[2][4], swl[2][4];

  // ---- tie resolution (smallest anchor indices first) ----
  unsigned cnt = meta[img].cnt;
  unsigned need = meta[img].ties_needed;
  unsigned nt = meta[img].tie_cnt;
  if (nt > TIE_CAP) nt = TIE_CAP;
  if (need > nt) need = nt;
  float scK = unflipKey(meta[img].K);
  int prev = -1;
  for (unsigned j = 0; j < need; ++j) {
    unsigned local = 0xFFFFFFFFu;
    for (unsigned p = tid; p < nt; p += 256) {
      unsigned v = ties[(size_t)img * TIE_CAP + p];
      if ((int)v > prev && v < local) local = v;
    }
    redu[tid] = local;
    __syncthreads();
    for (int o = 128; o > 0; o >>= 1) {
      if (tid < o) {
        unsigned a = redu[tid + o];
        if (a < redu[tid]) redu[tid] = a;
      }
      __syncthreads();
    }
    unsigned mm = redu[0];
    __syncthreads();
    if (tid == 0)
      decode_write(img, cnt + j, (int)mm, regs, anchors, scK, ccs[(size_t)img * NN + mm],
                   preds[(size_t)img * NN + mm], cand);
    prev = (int)mm;
  }
  int n = (int)(cnt + need);
  __syncthreads();  // make tie decode_write (global) visible to the block

  // ---- load candidates ----
  float x1o[4], y1o[4], x2o[4], y2o[4], area[4];
  unsigned kh[4], kl[4];
#pragma unroll
  for (int j = 0; j < 4; ++j) {
    int c = j * 256 + tid;
    size_t o = (size_t)img * CAND_CAP + (size_t)c;
    bool v = c < n;
    float vx1 = cand[0 * S + o], vy1 = cand[1 * S + o];
    float vx2 = cand[2 * S + o], vy2 = cand[3 * S + o];
    float vobj = cand[4 * S + o], vcc = cand[5 * S + o];
    float vcp = cand[6 * S + o], vsc = cand[7 * S + o];
    unsigned vai = reinterpret_cast<const unsigned*>(cand + 8 * S)[o];
    if (!v) { vx1 = vy1 = vx2 = vy2 = 0.f; vobj = vcc = vcp = 0.f; vsc = NEGV; vai = 0x7FFFu; }
    float offv = vcp * 4096.0f;
    float a1 = vx1 + offv, b1 = vy1 + offv, a2 = vx2 + offv, b2 = vy2 + offv;
    float ar = (a2 - a1) * (b2 - b1);
    x1o[j] = a1; y1o[j] = b1; x2o[j] = a2; y2o[j] = b2; area[j] = ar;
    float* L = lds + (size_t)c * 12;
    L[0] = a1; L[1] = b1; L[2] = a2; L[3] = b2; L[4] = ar;
    L[5] = vx1; L[6] = vy1; L[7] = vx2; L[8] = vy2; L[9] = vobj; L[10] = vcc; L[11] = vcp;
    kh[j] = flipKey(vsc);
    kl[j] = (((0x7FFFu - vai) & 0x7FFFu) << 10) | (unsigned)c;
  }
  __syncthreads();

  const unsigned validThr = flipKey(NEGV * 0.5f);
  float* obase = out + (size_t)img * MAXDET * 7;

  for (int it = 0; it < MAXDET; ++it) {
    // local max over 4 candidates
    unsigned mh = kh[0], ml = kl[0];
#pragma unroll
    for (int j = 1; j < 4; ++j) {
      bool g = (kh[j] > mh) || ((kh[j] == mh) && (kl[j] > ml));
      mh = g ? kh[j] : mh;
      ml = g ? kl[j] : ml;
    }
    // wave64 max via DPP (result in lane 63)
    U64MAX_DPP(mh, ml, 0x111);  // row_shr:1
    U64MAX_DPP(mh, ml, 0x112);  // row_shr:2
    U64MAX_DPP(mh, ml, 0x114);  // row_shr:4
    U64MAX_DPP(mh, ml, 0x118);  // row_shr:8
    U64MAX_DPP(mh, ml, 0x142);  // row_bcast:15
    U64MAX_DPP(mh, ml, 0x143);  // row_bcast:31
    unsigned wh = (unsigned)__builtin_amdgcn_readlane((int)mh, 63);
    unsigned wl = (unsigned)__builtin_amdgcn_readlane((int)ml, 63);
    if (lane == 0) { swh[it & 1][wid] = wh; swl[it & 1][wid] = wl; }
    __syncthreads();
    unsigned bh = swh[it & 1][0], bl = swl[it & 1][0];
#pragma unroll
    for (int w = 1; w < 4; ++w) {
      unsigned hw2 = swh[it & 1][w], lw2 = swl[it & 1][w];
      bool g = (hw2 > bh) || ((hw2 == bh) && (lw2 > bl));
      bh = g ? hw2 : bh;
      bl = g ? lw2 : bl;
    }
    if (bh <= validThr) {  // no valid candidates remain: zero-fill rest, done
      for (int p = tid; p < (MAXDET - it) * 7; p += 256) obase[it * 7 + p] = 0.0f;
      break;
    }
    int slot = (int)(bl & 1023u);
    const float4* Lq = reinterpret_cast<const float4*>(lds + (size_t)slot * 12);
    float4 A = Lq[0];   // x1o,y1o,x2o,y2o
    float4 Bv = Lq[1];  // area,x1,y1,x2
    float4 C = Lq[2];   // y2,obj,cc,cp
    if (tid == 0) {
      float* row = obase + it * 7;
      row[0] = Bv.y; row[1] = Bv.z; row[2] = Bv.w; row[3] = C.x;
      row[4] = C.y; row[5] = C.z; row[6] = C.w;
    }
    float areaB = Bv.x;
#pragma unroll
    for (int j = 0; j < 4; ++j) {
      if (slot == j * 256 + tid) { kh[j] = 0u; kl[j] = 0u; }
      float lx = fmaxf(A.x, x1o[j]), ly = fmaxf(A.y, y1o[j]);
      float rx = fminf(A.z, x2o[j]), ry = fminf(A.w, y2o[j]);
      float iw = fmaxf(rx - lx, 0.f), ih = fmaxf(ry - ly, 0.f);
      float inter = iw * ih;
      float uu = areaB + area[j] - inter;
      float ss = fmaf(2.0f, inter, -uu);  // exact 2i-u in the decision region (Sterbenz)
      float tt = uu * 0x1p-24f;           // exact scale
      if (uu > 0.f && ss > tt) { kh[j] = 0u; kl[j] = 0u; }
    }
  }
}

// ---------------- launch ----------------
extern "C" void kernel_launch(void* const* d_in, const int* in_sizes, int n_in,
                              void* d_out, int out_size, void* d_ws, size_t ws_size,
                              hipStream_t stream) {
  const float* regs = (const float*)d_in[0];
  const float* clses = (const float*)d_in[1];
  const float* anchors = (const float*)d_in[2];
  float* out = (float*)d_out;
  char* ws = (char*)d_ws;

  constexpr size_t HIST_BYTES = (size_t)BB * 65536 * 4;  // 4 MiB each
  constexpr size_t META_OFF = 2 * HIST_BYTES;
  constexpr size_t META_BYTES = 1024;
  constexpr size_t KEYS_OFF = META_OFF + META_BYTES;
  constexpr size_t ARR_BYTES = (size_t)BB * NN * 4;
  constexpr size_t CCS_OFF = KEYS_OFF + ARR_BYTES;
  constexpr size_t PREDS_OFF = CCS_OFF + ARR_BYTES;
  constexpr size_t CAND_OFF = PREDS_OFF + ARR_BYTES;
  constexpr size_t CAND_BYTES = (size_t)10 * BB * CAND_CAP * 4;
  constexpr size_t TIES_OFF = CAND_OFF + CAND_BYTES;

  unsigned* hist1 = (unsigned*)(ws);
  unsigned* hist2 = (unsigned*)(ws + HIST_BYTES);
  Meta* meta = (Meta*)(ws + META_OFF);
  unsigned* keys = (unsigned*)(ws + KEYS_OFF);
  float* ccs = (float*)(ws + CCS_OFF);
  int* preds = (int*)(ws + PREDS_OFF);
  float* cand = (float*)(ws + CAND_OFF);
  unsigned* ties = (unsigned*)(ws + TIES_OFF);

  // zero hist1 + hist2 + meta every launch (ws is not re-poisoned between replays)
  hipMemsetAsync(d_ws, 0, KEYS_OFF, stream);

  int blocks = (BB * NN + 255) / 256;
  k_score<<<BB * NN * 4 / 256, 256, 0, stream>>>(regs, clses, keys, ccs, preds, hist1);
  k_scan<<<BB, 256, 0, stream>>>(hist1, meta, 1);
  k_hist2<<<blocks, 256, 0, stream>>>(keys, meta, hist2);
  k_scan<<<BB, 256, 0, stream>>>(hist2, meta, 2);
  k_compact<<<blocks, 256, 0, stream>>>(regs, anchors, keys, ccs, preds, meta, cand, ties);
  k_nms<<<BB, 256, 0, stream>>>(cand, meta, out, regs, anchors, ccs, preds, ties);
}